// Round 5
// baseline (151.610 us; speedup 1.0000x reference)
//
#include <hip/hip_runtime.h>

#define B_    512
#define IN_   256
#define H_    512
#define OUT_  64
#define NDEATH (B_ - 1)
#define NSORT  512          // NDEATH padded to pow2 for bitonic sort / bsearch
#define RTOL_ 1e-6
#define ATOL_ 1e-8
#define NBLK  256
#define NTHR  512           // 8 waves/block -> 2 waves/SIMD

typedef __attribute__((ext_vector_type(4))) double d4_t;

// agent-visible store: relaxed atomic, bypasses L2 -> lands at L3 coherence
// point. No dirty L2 lines => barriers need NO wbl2/inv fences. (R11-verified)
__device__ __forceinline__ void ast(double* p, double v) {
    __hip_atomic_store(p, v, __ATOMIC_RELAXED, __HIP_MEMORY_SCOPE_AGENT);
}
__device__ __forceinline__ double ald(const double* p) {
    return __hip_atomic_load(p, __ATOMIC_RELAXED, __HIP_MEMORY_SCOPE_AGENT);
}
__device__ __forceinline__ unsigned aldu(const unsigned* p) {
    return __hip_atomic_load(p, __ATOMIC_RELAXED, __HIP_MEMORY_SCOPE_AGENT);
}
__device__ __forceinline__ void aadd(unsigned* p) {
    __hip_atomic_fetch_add(p, 1u, __ATOMIC_RELAXED, __HIP_MEMORY_SCOPE_AGENT);
}

// ---------------------------------------------------------------------------
// 16-way group barrier (R11-verified protocol). Full __syncthreads REQUIRED:
// the vmcnt(0) drain makes prior ast stores visible before the arrival.
// ---------------------------------------------------------------------------
__device__ __forceinline__ void gbar(unsigned* cnt, unsigned nb) {
    __syncthreads();
    if (threadIdx.x == 0) {
        aadd(cnt);
        while (aldu(cnt) < nb) __builtin_amdgcn_s_sleep(1);
    }
    __syncthreads();
}

// ---------------------------------------------------------------------------
// two-level device barrier (R16): 16-way group arrivals in parallel + 16-way
// root promoted by group leaders. All blocks release on root==16.
// ---------------------------------------------------------------------------
__device__ __forceinline__ void gbar2(unsigned* gslot, unsigned* root,
                                      int leader) {
    __syncthreads();
    if (threadIdx.x == 0) {
        aadd(gslot);
        if (leader) {
            while (aldu(gslot) < 16u) __builtin_amdgcn_s_sleep(1);
            aadd(root);
        }
        while (aldu(root) < 16u) __builtin_amdgcn_s_sleep(1);
    }
    __syncthreads();
}

// ---------------------------------------------------------------------------
// per-block: bitonic-sort deaths into LDS, emit sorted tolerance windows.
// 512 threads (1 elem/thread fill, 256 comparators/round).
// ---------------------------------------------------------------------------
__device__ void sort_windows(const float* __restrict__ deaths,
                             double* sd, double* slo, double* shi, int t) {
    if (t < NSORT) sd[t] = (t < NDEATH) ? (double)deaths[t] : 1e300;
    __syncthreads();
    for (int k = 2; k <= NSORT; k <<= 1) {
        for (int j = k >> 1; j > 0; j >>= 1) {
            if (t < 256) {
                int l = ((t & ~(j - 1)) << 1) | (t & (j - 1));   // pair (l, l+j)
                int p = l + j;
                bool up = ((l & k) == 0);
                double a = sd[l], b = sd[p];
                if ((a > b) == up) { sd[l] = b; sd[p] = a; }
            }
            __syncthreads();
        }
    }
    if (t < NSORT) {
        double d = sd[t];
        double w = ATOL_ + RTOL_ * fabs(d);
        slo[t] = d - w;
        shi[t] = d + w;
    }
    __syncthreads();
}

// ---------------------------------------------------------------------------
// f64 MFMA GEMM phase, R18: ZERO LDS staging, ZERO in-loop barriers.
// 8 waves = 4 independent 16x16 output chunks x 2 K-halves. Both A and B are
// loaded DIRECT global->register (A: lane=row, 16 rows x 32B per instr,
// consecutive k-chunks hit the same 64B lines -> L1/L2 served; B: 16 lanes
// read consecutive cols). Depth-3 register ring; K templated so the k-loop
// fully unrolls (ring indices static -> no scratch). One __syncthreads for
// the split-K exchange. Summation order identical to R16 (same 32-k chunks,
// same c4a/c4b split, same kw0+kw1 exchange) -> bit-identical numerics.
// ---------------------------------------------------------------------------
template <typename TIN, bool RELU, int N, int K>
__device__ void gemm_dev(const TIN* __restrict__ A, const float* __restrict__ W,
                         const float* __restrict__ bias, double* __restrict__ C,
                         int tile, int t, double (&cEx)[4][16][17]) {
    const int lane  = t & 63;
    const int chunk = (t >> 6) & 3;     // output chunk: wm=chunk&1, wn=chunk>>1
    const int wm    = chunk & 1;
    const int wn    = chunk >> 1;
    const int kw    = t >> 8;           // K-half
    constexpr int nbx = N >> 5;
    const int row0  = (tile / nbx) << 5;
    const int col0  = (tile % nbx) << 5;

    const int mrow  = lane & 15;        // row within chunk (also col for B)
    const int kq    = lane >> 4;        // k sub-step 0..3
    const int kbase = kw * (K >> 1);
    constexpr int nkt = K >> 6;         // 32-k chunks per K-half

    const TIN*   ap = A + (size_t)(row0 + wm * 16 + mrow) * K + kbase + kq;
    const float* wp = W + (size_t)(kbase + kq) * N + col0 + wn * 16 + mrow;

    double ar[3][8];
    float  br[3][8];

    auto load_ab = [&](int rs, int kt) {
        const int k0 = kt << 5;
        #pragma unroll
        for (int i = 0; i < 8; ++i) {
            ar[rs][i] = (double)ap[k0 + 4 * i];
            br[rs][i] = wp[(size_t)(k0 + 4 * i) * N];
        }
    };

    load_ab(0, 0);
    if (nkt > 1) load_ab(1, 1);
    if (nkt > 2) load_ab(2, 2);

    d4_t c4a = {0.0, 0.0, 0.0, 0.0};
    d4_t c4b = {0.0, 0.0, 0.0, 0.0};

    #pragma unroll
    for (int kt = 0; kt < nkt; ++kt) {
        const int rs = kt % 3;
        #pragma unroll
        for (int ks = 0; ks < 4; ++ks)
            c4a = __builtin_amdgcn_mfma_f64_16x16x4f64(ar[rs][ks],
                      (double)br[rs][ks], c4a, 0, 0, 0);
        #pragma unroll
        for (int ks = 4; ks < 8; ++ks)
            c4b = __builtin_amdgcn_mfma_f64_16x16x4f64(ar[rs][ks],
                      (double)br[rs][ks], c4b, 0, 0, 0);
        if (kt + 3 < nkt) load_ab(rs, kt + 3);   // refill consumed ring slot
    }

    d4_t c4 = c4a + c4b;

    // combine K-half partials: kw1 publishes, kw0 adds + epilogue.
    const int r4 = (lane >> 4) * 4;
    if (kw == 1) {
        #pragma unroll
        for (int r = 0; r < 4; ++r)
            cEx[chunk][r4 + r][lane & 15] = c4[r];
    }
    __syncthreads();
    if (kw == 0) {
        #pragma unroll
        for (int r = 0; r < 4; ++r) {
            int row = row0 + wm * 16 + r4 + r;
            int col = col0 + wn * 16 + (lane & 15);
            double v = c4[r] + cEx[chunk][r4 + r][lane & 15] + (double)bias[col];
            if (RELU) v = v > 0.0 ? v : 0.0;
            ast(&C[(size_t)row * N + col], v);
        }
    }
}

// ---------------------------------------------------------------------------
// column c: mean + target-MSE partial + compactness partial -> global slots
// 512 threads, one row per thread.
// ---------------------------------------------------------------------------
__device__ void mc_dev(const float* __restrict__ target,
                       const double* __restrict__ y,
                       double* __restrict__ t_part, double* __restrict__ c_part,
                       int c, int t) {
    const int wave = t >> 6, lane = t & 63;
    double v = y[(size_t)t * OUT_ + c];
    double s = v;
    for (int off = 32; off; off >>= 1) s += __shfl_down(s, off);
    __shared__ double swm[8];
    __shared__ double smean;
    if (lane == 0) swm[wave] = s;
    __syncthreads();
    if (t == 0) {
        double m = 0.0;
        #pragma unroll
        for (int w = 0; w < 8; ++w) m += swm[w];
        smean = m / (double)B_;
    }
    __syncthreads();
    double m = smean;
    double d = (double)target[(size_t)t * OUT_ + c] - v;
    double t_s = d * d;
    double c_s = fabs(v - m);
    for (int off = 32; off; off >>= 1) {
        t_s += __shfl_down(t_s, off);
        c_s += __shfl_down(c_s, off);
    }
    __shared__ double st[8], sc[8];
    if (lane == 0) { st[wave] = t_s; sc[wave] = c_s; }
    __syncthreads();
    if (t == 0) {
        double ts = 0.0, cs = 0.0;
        #pragma unroll
        for (int w = 0; w < 8; ++w) { ts += st[w]; cs += sc[w]; }
        ast(&t_part[c], ts);
        ast(&c_part[c], cs);
    }
}

// ---------------------------------------------------------------------------
// pdist + sorted-window match. Block b: rows b and 510-b (512 pairs, balanced).
// ---------------------------------------------------------------------------
__device__ __forceinline__ double pair_val(const double* __restrict__ yrow_s,
                                           const double* __restrict__ yj,
                                           const double* __restrict__ slo,
                                           const double* __restrict__ shi) {
    double s = 0.0;
    #pragma unroll
    for (int d = 0; d < OUT_; d += 2) {
        double2 v = *(const double2*)(yj + d);
        double d0 = yrow_s[d]     - v.x;
        double d1 = yrow_s[d + 1] - v.y;
        s = fma(d0, d0, s);
        s = fma(d1, d1, s);
    }
    double pd = sqrt(s);
    int pos = 0;
    #pragma unroll
    for (int step = NSORT / 2; step; step >>= 1) {
        if (slo[pos + step - 1] <= pd) pos += step;
    }
    bool m = (pos > 0) && (shi[pos - 1] >= pd);
    return m ? pd : 0.0;
}

__device__ void pdist_dev(const double* __restrict__ y,
                          double* __restrict__ hom_part, int bid, int t,
                          double* yA, double* yB,
                          const double* slo, const double* shi) {
    const int iA = bid;
    const int iB = 510 - bid;     // == iA when bid == 255
    if (t < OUT_)            yA[t]        = y[(size_t)iA * OUT_ + t];
    else if (t < 2 * OUT_)   yB[t - OUT_] = y[(size_t)iB * OUT_ + (t - OUT_)];
    __syncthreads();

    double local = 0.0;
    for (int j = iA + 1 + t; j < B_; j += NTHR)
        local += pair_val(yA, y + (size_t)j * OUT_, slo, shi);
    if (iB != iA)
        for (int j = iB + 1 + t; j < B_; j += NTHR)
            local += pair_val(yB, y + (size_t)j * OUT_, slo, shi);

    for (int off = 32; off; off >>= 1) local += __shfl_down(local, off);
    __shared__ double sw[8];
    int wave = t >> 6, lane = t & 63;
    if (lane == 0) sw[wave] = local;
    __syncthreads();
    if (t == 0) {
        double s = 0.0;
        #pragma unroll
        for (int w = 0; w < 8; ++w) s += sw[w];
        ast(&hom_part[bid], s);
    }
}

// ---------------------------------------------------------------------------
// single fused persistent kernel, R18: 256 blocks x 512 threads.
// XCD-LOCAL groups: bid -> g=(bid&7)|((bid>>7)<<3), c=(bid>>3)&15, so all 16
// blocks of group g share one XCD (bid%8 round-robin) -> A-strip re-reads hit
// the same L2, barrier lines die-local. Group g owns 32-row strip g; P0..P2
// group-local 16-arrival barriers; two-level device barrier before pdist;
// two-level finalize with block 0 as fixed finalizer.
// Counters (uints): grp g slot p -> cnt[g*32+p] (p=0..4); pdist root cnt[512];
// finalize root cnt[513]. Window broadcast: wbc[0..511]=lo, wbc[512..1023]=hi.
// ---------------------------------------------------------------------------
__global__ __launch_bounds__(NTHR) void fused_k(
    const float* __restrict__ batch, const float* __restrict__ target,
    const float* __restrict__ W1, const float* __restrict__ b1,
    const float* __restrict__ W2, const float* __restrict__ b2,
    const float* __restrict__ W3, const float* __restrict__ b3,
    const float* __restrict__ Wout, const float* __restrict__ bout,
    const float* __restrict__ deaths, float* __restrict__ out,
    double* __restrict__ hA, double* __restrict__ hB,
    double* __restrict__ hC, double* __restrict__ yv,
    double* __restrict__ hom_part, double* __restrict__ t_part,
    double* __restrict__ c_part, unsigned* __restrict__ cnt,
    double* __restrict__ wbc) {
    const int bid = blockIdx.x;
    const int t   = threadIdx.x;
    const int g   = (bid & 7) | ((bid >> 7) << 3);  // XCD-local group
    const int c   = (bid >> 3) & 15;                // col-tile within group
    const int tile = g * 16 + c;                    // row0=32g, col0=32c
    unsigned* gc  = cnt + g * 32;                   // group counter line

    __shared__ double cEx[4][16][17];
    __shared__ double slo[NSORT], shi[NSORT];
    __shared__ double yA[OUT_], yB[OUT_];
    double* sd = &cEx[0][0][0];               // sort scratch alias (512 dbl)

    // P0..P2: three GEMMs; tile index (row0=32g, col0=32c).
    gemm_dev<float,  true, H_, IN_>(batch, W1, b1, hA, tile, t, cEx);
    gbar(&gc[0], 16);
    gemm_dev<double, true, H_, H_>(hA, W2, b2, hB, tile, t, cEx);
    gbar(&gc[1], 16);
    gemm_dev<double, true, H_, H_>(hB, W3, b3, hC, tile, t, cEx);
    gbar(&gc[2], 16);

    // P3: Wout tile g*2+c on c<2 (32-row strip g -> group-local dep); c>=2
    // sort. Block (g0,c2) publishes the sorted windows for the c<2 blocks.
    if (c < 2) {
        gemm_dev<double, false, OUT_, H_>(hC, Wout, bout, yv, g * 2 + c, t, cEx);
    } else {
        sort_windows(deaths, sd, slo, shi, t);
        if (g == 0 && c == 2 && t < NSORT) {
            ast(&wbc[t],         slo[t]);
            ast(&wbc[NSORT + t], shi[t]);
        }
    }

    // two-level device barrier: pdist needs all of yv + window broadcast
    gbar2(&gc[3], &cnt[512], c == 0);
    if (c < 2) {
        if (t < NSORT) {
            slo[t] = ald(&wbc[t]);
            shi[t] = ald(&wbc[NSORT + t]);
        }
        __syncthreads();
    }

    // P4: pdist on all 256 blocks; mean/MSE/compactness on blocks 0..63
    pdist_dev(yv, hom_part, bid, t, yA, yB, slo, shi);
    if (bid < OUT_) mc_dev(target, yv, t_part, c_part, bid, t);

    // P5: two-level finalize arrivals; block 0 is the fixed finalizer.
    __syncthreads();   // vmcnt(0) drain: part stores visible before arrival
    if (t == 0) {
        aadd(&gc[4]);
        if (c == 0) {
            while (aldu(&gc[4]) < 16u) __builtin_amdgcn_s_sleep(1);
            aadd(&cnt[513]);
        }
    }
    if (bid != 0) return;
    if (t == 0)
        while (aldu(&cnt[513]) < 16u) __builtin_amdgcn_s_sleep(1);
    __syncthreads();

    {
        double h = 0.0, tp = 0.0, cp = 0.0;
        if (t < NBLK) h = ald(&hom_part[t]);
        if (t < OUT_) { tp = ald(&t_part[t]); cp = ald(&c_part[t]); }
        for (int off = 32; off; off >>= 1) {
            h  += __shfl_down(h,  off);
            tp += __shfl_down(tp, off);
            cp += __shfl_down(cp, off);
        }
        __shared__ double sh[8], stp[8], scp[8];
        int wave = t >> 6, lane = t & 63;
        if (lane == 0) { sh[wave] = h; stp[wave] = tp; scp[wave] = cp; }
        __syncthreads();
        if (t == 0) {
            double hs = 0.0, ts = 0.0, cs = 0.0;
            #pragma unroll
            for (int w = 0; w < 8; ++w) {
                hs += sh[w]; ts += stp[w]; cs += scp[w];
            }
            out[0] = (float)(ts / (double)(B_ * OUT_) + hs + 0.01 * cs);
        }
    }
}

extern "C" void kernel_launch(void* const* d_in, const int* in_sizes, int n_in,
                              void* d_out, int out_size, void* d_ws, size_t ws_size,
                              hipStream_t stream) {
    const float* batch  = (const float*)d_in[0];
    const float* target = (const float*)d_in[1];
    const float* W1     = (const float*)d_in[2];
    const float* b1     = (const float*)d_in[3];
    const float* W2     = (const float*)d_in[4];
    const float* b2     = (const float*)d_in[5];
    const float* W3     = (const float*)d_in[6];
    const float* b3     = (const float*)d_in[7];
    const float* Wout   = (const float*)d_in[8];
    const float* bout   = (const float*)d_in[9];
    const float* deaths = (const float*)d_in[10];
    float* out = (float*)d_out;

    double* hA       = (double*)d_ws;              // 512*512
    double* hB       = hA + (size_t)B_ * H_;       // 512*512
    double* hC       = hB + (size_t)B_ * H_;       // 512*512
    double* yv       = hC + (size_t)B_ * H_;       // 512*64
    double* hom_part = yv + (size_t)B_ * OUT_;     // 256
    double* t_part   = hom_part + NBLK;            // 64
    double* c_part   = t_part + OUT_;              // 64
    unsigned* cnt    = (unsigned*)(c_part + OUT_); // 576 uints
    double* wbc      = (double*)(cnt + 576);       // 1024 doubles (lo|hi)

    hipMemsetAsync(cnt, 0, 576 * sizeof(unsigned), stream);

    fused_k<<<dim3(NBLK), dim3(NTHR), 0, stream>>>(
        batch, target, W1, b1, W2, b2, W3, b3, Wout, bout, deaths, out,
        hA, hB, hC, yv, hom_part, t_part, c_part, cnt, wbc);
}

// Round 6
// 125.479 us; speedup vs baseline: 1.2083x; 1.2083x over previous
//
#include <hip/hip_runtime.h>

#define B_    512
#define IN_   256
#define H_    512
#define OUT_  64
#define NDEATH (B_ - 1)
#define NSORT  512          // NDEATH padded to pow2 for bitonic sort / bsearch
#define RTOL_ 1e-6
#define ATOL_ 1e-8
#define NBLK  256
#define NTHR  512           // 8 waves/block -> 2 waves/SIMD
#define KT    32            // K-tile (per wavegroup), split-K x2

typedef __attribute__((ext_vector_type(4))) double d4_t;

// agent-visible store: relaxed atomic, bypasses L2 -> lands at L3 coherence
// point. No dirty L2 lines => barriers need NO wbl2/inv fences. (R11-verified)
__device__ __forceinline__ void ast(double* p, double v) {
    __hip_atomic_store(p, v, __ATOMIC_RELAXED, __HIP_MEMORY_SCOPE_AGENT);
}
__device__ __forceinline__ double ald(const double* p) {
    return __hip_atomic_load(p, __ATOMIC_RELAXED, __HIP_MEMORY_SCOPE_AGENT);
}
__device__ __forceinline__ unsigned aldu(const unsigned* p) {
    return __hip_atomic_load(p, __ATOMIC_RELAXED, __HIP_MEMORY_SCOPE_AGENT);
}
__device__ __forceinline__ void aadd(unsigned* p) {
    __hip_atomic_fetch_add(p, 1u, __ATOMIC_RELAXED, __HIP_MEMORY_SCOPE_AGENT);
}

// ---------------------------------------------------------------------------
// LDS-only barrier (R15): lgkmcnt(0)+s_barrier. Global prefetches ride across;
// the K-loop's only cross-wave dependency is LDS staging.
// ---------------------------------------------------------------------------
__device__ __forceinline__ void lbar() {
    asm volatile("s_waitcnt lgkmcnt(0)" ::: "memory");
    __builtin_amdgcn_s_barrier();
    asm volatile("" ::: "memory");
}

// ---------------------------------------------------------------------------
// 16-way group barrier (R11-verified protocol). Full __syncthreads REQUIRED:
// the vmcnt(0) drain makes prior ast stores visible before the arrival.
// ---------------------------------------------------------------------------
__device__ __forceinline__ void gbar(unsigned* cnt, unsigned nb) {
    __syncthreads();
    if (threadIdx.x == 0) {
        aadd(cnt);
        while (aldu(cnt) < nb) __builtin_amdgcn_s_sleep(1);
    }
    __syncthreads();
}

// ---------------------------------------------------------------------------
// two-level device barrier (R16): 16-way group arrivals in parallel + 16-way
// root promoted by group leaders. All blocks release on root==16.
// ---------------------------------------------------------------------------
__device__ __forceinline__ void gbar2(unsigned* gslot, unsigned* root,
                                      int leader) {
    __syncthreads();
    if (threadIdx.x == 0) {
        aadd(gslot);
        if (leader) {
            while (aldu(gslot) < 16u) __builtin_amdgcn_s_sleep(1);
            aadd(root);
        }
        while (aldu(root) < 16u) __builtin_amdgcn_s_sleep(1);
    }
    __syncthreads();
}

// ---------------------------------------------------------------------------
// per-block: bitonic-sort deaths into LDS, emit sorted tolerance windows.
// 512 threads (1 elem/thread fill, 256 comparators/round).
// ---------------------------------------------------------------------------
__device__ void sort_windows(const float* __restrict__ deaths,
                             double* sd, double* slo, double* shi, int t) {
    if (t < NSORT) sd[t] = (t < NDEATH) ? (double)deaths[t] : 1e300;
    __syncthreads();
    for (int k = 2; k <= NSORT; k <<= 1) {
        for (int j = k >> 1; j > 0; j >>= 1) {
            if (t < 256) {
                int l = ((t & ~(j - 1)) << 1) | (t & (j - 1));   // pair (l, l+j)
                int p = l + j;
                bool up = ((l & k) == 0);
                double a = sd[l], b = sd[p];
                if ((a > b) == up) { sd[l] = b; sd[p] = a; }
            }
            __syncthreads();
        }
    }
    if (t < NSORT) {
        double d = sd[t];
        double w = ATOL_ + RTOL_ * fabs(d);
        slo[t] = d - w;
        shi[t] = d + w;
    }
    __syncthreads();
}

// ---------------------------------------------------------------------------
// f64 MFMA GEMM phase (R16 structure, verified): split-K x2 across wavegroups;
// A staged via LDS (depth-3 register prefetch); B direct global->reg
// (coalesced, per-wave private); two accumulators split the MFMA chain.
// One lgkm-only barrier per K-tile. R19: s_setprio(1) around MFMA cluster.
// ---------------------------------------------------------------------------
template <typename TIN, bool RELU>
__device__ void gemm_dev(const TIN* __restrict__ A, const float* __restrict__ W,
                         const float* __restrict__ bias, double* __restrict__ C,
                         int N, int K, int tile, int t,
                         double (&As)[2][2][KT][33]) {
    const int lane  = t & 63;
    const int wave4 = (t >> 6) & 3;     // quarter selector (same for both wg)
    const int w2    = t >> 8;           // wavegroup = K-half
    const int tg    = t & 255;          // 256-thread-local id for staging map
    const int wm    = wave4 & 1, wn = wave4 >> 1;
    const int nbx   = N >> 5;
    const int row0  = (tile / nbx) << 5;
    const int col0  = (tile % nbx) << 5;

    const int akk   = tg & 31;          // k within A tile
    const int amm   = tg >> 5;          // base row (rows amm+8p, p=0..3)
    const int kbase = w2 * (K >> 1);
    const int nkt   = K >> 6;           // K-tiles per wavegroup

    const int mrow  = wm * 16 + (lane & 15);
    const int ncol  = wn * 16 + (lane & 15);
    const int kq    = lane >> 4;

    TIN   ar[3][4];
    float br[3][8];

    auto load_a = [&](int rs, int kt) {
        const int k0 = kbase + (kt << 5);
        #pragma unroll
        for (int p = 0; p < 4; ++p)
            ar[rs][p] = A[(size_t)(row0 + amm + 8 * p) * K + k0 + akk];
    };
    auto load_b = [&](int rs, int kt) {
        const int k0 = kbase + (kt << 5);
        const float* wp = W + (size_t)(k0 + kq) * N + col0 + ncol;
        #pragma unroll
        for (int ks = 0; ks < 8; ++ks)
            br[rs][ks] = wp[(size_t)(4 * ks) * N];
    };
    auto stage_a = [&](int rs, int buf) {
        #pragma unroll
        for (int p = 0; p < 4; ++p)
            As[w2][buf][akk][amm + 8 * p] = (double)ar[rs][p];
    };

    load_a(0, 0); load_b(0, 0);
    if (nkt > 1) { load_a(1, 1); load_b(1, 1); }
    if (nkt > 2) { load_a(2, 2); load_b(2, 2); }
    stage_a(0, 0);
    lbar();

    d4_t c4a = {0.0, 0.0, 0.0, 0.0};
    d4_t c4b = {0.0, 0.0, 0.0, 0.0};

    for (int kt = 0; kt < nkt; ++kt) {
        const int cur = kt & 1;
        const int rs  = kt % 3;
        __builtin_amdgcn_s_setprio(1);
        #pragma unroll
        for (int ks = 0; ks < 4; ++ks) {
            double av = As[w2][cur][ks * 4 + kq][mrow];
            c4a = __builtin_amdgcn_mfma_f64_16x16x4f64(av, (double)br[rs][ks],
                                                       c4a, 0, 0, 0);
        }
        #pragma unroll
        for (int ks = 4; ks < 8; ++ks) {
            double av = As[w2][cur][ks * 4 + kq][mrow];
            c4b = __builtin_amdgcn_mfma_f64_16x16x4f64(av, (double)br[rs][ks],
                                                       c4b, 0, 0, 0);
        }
        __builtin_amdgcn_s_setprio(0);
        // slot rs fully consumed -> refill for kt+3
        if (kt + 3 < nkt) { load_a(rs, kt + 3); load_b(rs, kt + 3); }
        if (kt + 1 < nkt) stage_a((kt + 1) % 3, cur ^ 1); // disjoint buffer
        lbar();                                           // lgkm-only
    }

    d4_t c4 = c4a + c4b;

    // combine K-half partials: kw1 publishes, kw0 adds + epilogue.
    // cEx aliases As (all K-loop reads fenced by the final loop barrier).
    double (*cEx)[16][17] = (double (*)[16][17])(&As[0][0][0][0]);
    const int r4 = (lane >> 4) * 4;
    if (w2 == 1) {
        #pragma unroll
        for (int r = 0; r < 4; ++r)
            cEx[wave4][r4 + r][lane & 15] = c4[r];
    }
    lbar();
    if (w2 == 0) {
        #pragma unroll
        for (int r = 0; r < 4; ++r) {
            int row = row0 + wm * 16 + r4 + r;
            int col = col0 + wn * 16 + (lane & 15);
            double v = c4[r] + cEx[wave4][r4 + r][lane & 15] + (double)bias[col];
            if (RELU) v = v > 0.0 ? v : 0.0;
            ast(&C[(size_t)row * N + col], v);
        }
    }
}

// ---------------------------------------------------------------------------
// column c: mean + target-MSE partial + compactness partial -> global slots
// 512 threads, one row per thread.
// ---------------------------------------------------------------------------
__device__ void mc_dev(const float* __restrict__ target,
                       const double* __restrict__ y,
                       double* __restrict__ t_part, double* __restrict__ c_part,
                       int c, int t) {
    const int wave = t >> 6, lane = t & 63;
    double v = y[(size_t)t * OUT_ + c];
    double s = v;
    for (int off = 32; off; off >>= 1) s += __shfl_down(s, off);
    __shared__ double swm[8];
    __shared__ double smean;
    if (lane == 0) swm[wave] = s;
    __syncthreads();
    if (t == 0) {
        double m = 0.0;
        #pragma unroll
        for (int w = 0; w < 8; ++w) m += swm[w];
        smean = m / (double)B_;
    }
    __syncthreads();
    double m = smean;
    double d = (double)target[(size_t)t * OUT_ + c] - v;
    double t_s = d * d;
    double c_s = fabs(v - m);
    for (int off = 32; off; off >>= 1) {
        t_s += __shfl_down(t_s, off);
        c_s += __shfl_down(c_s, off);
    }
    __shared__ double st[8], sc[8];
    if (lane == 0) { st[wave] = t_s; sc[wave] = c_s; }
    __syncthreads();
    if (t == 0) {
        double ts = 0.0, cs = 0.0;
        #pragma unroll
        for (int w = 0; w < 8; ++w) { ts += st[w]; cs += sc[w]; }
        ast(&t_part[c], ts);
        ast(&c_part[c], cs);
    }
}

// ---------------------------------------------------------------------------
// pdist + sorted-window match. Block b: rows b and 510-b (512 pairs, balanced).
// ---------------------------------------------------------------------------
__device__ __forceinline__ double pair_val(const double* __restrict__ yrow_s,
                                           const double* __restrict__ yj,
                                           const double* __restrict__ slo,
                                           const double* __restrict__ shi) {
    double s = 0.0;
    #pragma unroll
    for (int d = 0; d < OUT_; d += 2) {
        double2 v = *(const double2*)(yj + d);
        double d0 = yrow_s[d]     - v.x;
        double d1 = yrow_s[d + 1] - v.y;
        s = fma(d0, d0, s);
        s = fma(d1, d1, s);
    }
    double pd = sqrt(s);
    int pos = 0;
    #pragma unroll
    for (int step = NSORT / 2; step; step >>= 1) {
        if (slo[pos + step - 1] <= pd) pos += step;
    }
    bool m = (pos > 0) && (shi[pos - 1] >= pd);
    return m ? pd : 0.0;
}

__device__ void pdist_dev(const double* __restrict__ y,
                          double* __restrict__ hom_part, int bid, int t,
                          double* yA, double* yB,
                          const double* slo, const double* shi) {
    const int iA = bid;
    const int iB = 510 - bid;     // == iA when bid == 255
    if (t < OUT_)            yA[t]        = y[(size_t)iA * OUT_ + t];
    else if (t < 2 * OUT_)   yB[t - OUT_] = y[(size_t)iB * OUT_ + (t - OUT_)];
    __syncthreads();

    double local = 0.0;
    for (int j = iA + 1 + t; j < B_; j += NTHR)
        local += pair_val(yA, y + (size_t)j * OUT_, slo, shi);
    if (iB != iA)
        for (int j = iB + 1 + t; j < B_; j += NTHR)
            local += pair_val(yB, y + (size_t)j * OUT_, slo, shi);

    for (int off = 32; off; off >>= 1) local += __shfl_down(local, off);
    __shared__ double sw[8];
    int wave = t >> 6, lane = t & 63;
    if (lane == 0) sw[wave] = local;
    __syncthreads();
    if (t == 0) {
        double s = 0.0;
        #pragma unroll
        for (int w = 0; w < 8; ++w) s += sw[w];
        ast(&hom_part[bid], s);
    }
}

// ---------------------------------------------------------------------------
// single fused persistent kernel, R19: 256 blocks x 512 threads.
// XCD-LOCAL groups: bid -> g=(bid&7)|((bid>>7)<<3), c=(bid>>3)&15 (bijective);
// all 16 blocks of group g share bid%8 -> one XCD. ast writes land in L3; the
// first same-XCD reader fills its L2 from L3, the other 15 blocks hit L2
// (normal loads are mapping-independent-correct: each buffer is write-once-
// read-once per launch, so no stale-L2 hazard). Group g owns 32-row strip g;
// P0..P2 group-local 16-arrival barriers; two-level device barrier before
// pdist; two-level finalize with block 0 as fixed finalizer.
// Counters (uints): grp g slot p -> cnt[g*32+p] (p=0..4); pdist root cnt[512];
// finalize root cnt[513]. Window broadcast: wbc[0..511]=lo, wbc[512..1023]=hi.
// ---------------------------------------------------------------------------
__global__ __launch_bounds__(NTHR) void fused_k(
    const float* __restrict__ batch, const float* __restrict__ target,
    const float* __restrict__ W1, const float* __restrict__ b1,
    const float* __restrict__ W2, const float* __restrict__ b2,
    const float* __restrict__ W3, const float* __restrict__ b3,
    const float* __restrict__ Wout, const float* __restrict__ bout,
    const float* __restrict__ deaths, float* __restrict__ out,
    double* __restrict__ hA, double* __restrict__ hB,
    double* __restrict__ hC, double* __restrict__ yv,
    double* __restrict__ hom_part, double* __restrict__ t_part,
    double* __restrict__ c_part, unsigned* __restrict__ cnt,
    double* __restrict__ wbc) {
    const int bid = blockIdx.x;
    const int t   = threadIdx.x;
    const int g   = (bid & 7) | ((bid >> 7) << 3);  // XCD-local group
    const int c   = (bid >> 3) & 15;                // col-tile within group
    const int tile = g * 16 + c;                    // row0=32g, col0=32c
    unsigned* gc  = cnt + g * 32;                   // group counter line

    __shared__ double As[2][2][KT][33];
    __shared__ double slo[NSORT], shi[NSORT];
    __shared__ double yA[OUT_], yB[OUT_];
    double* sd = &As[0][0][0][0];             // sort scratch alias (512 dbl)

    // P0..P2: three GEMMs; tile (row0=32g, col0=32c).
    gemm_dev<float,  true>(batch, W1, b1, hA, H_, IN_, tile, t, As);
    gbar(&gc[0], 16);
    gemm_dev<double, true>(hA, W2, b2, hB, H_, H_, tile, t, As);
    gbar(&gc[1], 16);
    gemm_dev<double, true>(hB, W3, b3, hC, H_, H_, tile, t, As);
    gbar(&gc[2], 16);

    // P3: Wout tile g*2+c on c<2 (32-row strip g -> group-local dep, same
    // XCD); c>=2 sort. Block (g0,c2) publishes windows for the c<2 blocks.
    if (c < 2) {
        gemm_dev<double, false>(hC, Wout, bout, yv, OUT_, H_, g * 2 + c, t, As);
    } else {
        sort_windows(deaths, sd, slo, shi, t);
        if (g == 0 && c == 2 && t < NSORT) {
            ast(&wbc[t],         slo[t]);
            ast(&wbc[NSORT + t], shi[t]);
        }
    }

    // two-level device barrier: pdist needs all of yv + window broadcast
    gbar2(&gc[3], &cnt[512], c == 0);
    if (c < 2) {
        if (t < NSORT) {
            slo[t] = ald(&wbc[t]);
            shi[t] = ald(&wbc[NSORT + t]);
        }
        __syncthreads();
    }

    // P4: pdist on all 256 blocks; mean/MSE/compactness on blocks 0..63
    pdist_dev(yv, hom_part, bid, t, yA, yB, slo, shi);
    if (bid < OUT_) mc_dev(target, yv, t_part, c_part, bid, t);

    // P5: two-level finalize arrivals; block 0 is the fixed finalizer.
    __syncthreads();   // vmcnt(0) drain: part stores visible before arrival
    if (t == 0) {
        aadd(&gc[4]);
        if (c == 0) {
            while (aldu(&gc[4]) < 16u) __builtin_amdgcn_s_sleep(1);
            aadd(&cnt[513]);
        }
    }
    if (bid != 0) return;
    if (t == 0)
        while (aldu(&cnt[513]) < 16u) __builtin_amdgcn_s_sleep(1);
    __syncthreads();

    {
        double h = 0.0, tp = 0.0, cp = 0.0;
        if (t < NBLK) h = ald(&hom_part[t]);
        if (t < OUT_) { tp = ald(&t_part[t]); cp = ald(&c_part[t]); }
        for (int off = 32; off; off >>= 1) {
            h  += __shfl_down(h,  off);
            tp += __shfl_down(tp, off);
            cp += __shfl_down(cp, off);
        }
        __shared__ double sh[8], stp[8], scp[8];
        int wave = t >> 6, lane = t & 63;
        if (lane == 0) { sh[wave] = h; stp[wave] = tp; scp[wave] = cp; }
        __syncthreads();
        if (t == 0) {
            double hs = 0.0, ts = 0.0, cs = 0.0;
            #pragma unroll
            for (int w = 0; w < 8; ++w) {
                hs += sh[w]; ts += stp[w]; cs += scp[w];
            }
            out[0] = (float)(ts / (double)(B_ * OUT_) + hs + 0.01 * cs);
        }
    }
}

extern "C" void kernel_launch(void* const* d_in, const int* in_sizes, int n_in,
                              void* d_out, int out_size, void* d_ws, size_t ws_size,
                              hipStream_t stream) {
    const float* batch  = (const float*)d_in[0];
    const float* target = (const float*)d_in[1];
    const float* W1     = (const float*)d_in[2];
    const float* b1     = (const float*)d_in[3];
    const float* W2     = (const float*)d_in[4];
    const float* b2     = (const float*)d_in[5];
    const float* W3     = (const float*)d_in[6];
    const float* b3     = (const float*)d_in[7];
    const float* Wout   = (const float*)d_in[8];
    const float* bout   = (const float*)d_in[9];
    const float* deaths = (const float*)d_in[10];
    float* out = (float*)d_out;

    double* hA       = (double*)d_ws;              // 512*512
    double* hB       = hA + (size_t)B_ * H_;       // 512*512
    double* hC       = hB + (size_t)B_ * H_;       // 512*512
    double* yv       = hC + (size_t)B_ * H_;       // 512*64
    double* hom_part = yv + (size_t)B_ * OUT_;     // 256
    double* t_part   = hom_part + NBLK;            // 64
    double* c_part   = t_part + OUT_;              // 64
    unsigned* cnt    = (unsigned*)(c_part + OUT_); // 576 uints
    double* wbc      = (double*)(cnt + 576);       // 1024 doubles (lo|hi)

    hipMemsetAsync(cnt, 0, 576 * sizeof(unsigned), stream);

    fused_k<<<dim3(NBLK), dim3(NTHR), 0, stream>>>(
        batch, target, W1, b1, W2, b2, W3, b3, Wout, bout, deaths, out,
        hA, hB, hC, yv, hom_part, t_part, c_part, cnt, wbc);
}

// Round 7
// 123.378 us; speedup vs baseline: 1.2288x; 1.0170x over previous
//
#include <hip/hip_runtime.h>

#define B_    512
#define IN_   256
#define H_    512
#define OUT_  64
#define NDEATH (B_ - 1)
#define NSORT  512          // NDEATH padded to pow2 for bitonic sort / bsearch
#define RTOL_ 1e-6
#define ATOL_ 1e-8
#define NBLK  256
#define NTHR  512           // 8 waves/block -> 2 waves/SIMD
#define KT    32            // K-tile (per wavegroup), split-K x2

typedef __attribute__((ext_vector_type(4))) double d4_t;

// agent-visible store: relaxed atomic, bypasses L2 -> lands at L3 coherence
// point. No dirty L2 lines => barriers need NO wbl2/inv fences. (R11-verified)
__device__ __forceinline__ void ast(double* p, double v) {
    __hip_atomic_store(p, v, __ATOMIC_RELAXED, __HIP_MEMORY_SCOPE_AGENT);
}
__device__ __forceinline__ double ald(const double* p) {
    return __hip_atomic_load(p, __ATOMIC_RELAXED, __HIP_MEMORY_SCOPE_AGENT);
}
__device__ __forceinline__ unsigned aldu(const unsigned* p) {
    return __hip_atomic_load(p, __ATOMIC_RELAXED, __HIP_MEMORY_SCOPE_AGENT);
}
__device__ __forceinline__ void aadd(unsigned* p) {
    __hip_atomic_fetch_add(p, 1u, __ATOMIC_RELAXED, __HIP_MEMORY_SCOPE_AGENT);
}

// ---------------------------------------------------------------------------
// LDS-only barrier (R15): lgkmcnt(0)+s_barrier. Global prefetches ride across;
// the K-loop's only cross-wave dependency is LDS staging.
// ---------------------------------------------------------------------------
__device__ __forceinline__ void lbar() {
    asm volatile("s_waitcnt lgkmcnt(0)" ::: "memory");
    __builtin_amdgcn_s_barrier();
    asm volatile("" ::: "memory");
}

// ---------------------------------------------------------------------------
// 16-way group barrier (R11-verified protocol). Full __syncthreads REQUIRED:
// the vmcnt(0) drain makes prior ast stores visible before the arrival.
// ---------------------------------------------------------------------------
__device__ __forceinline__ void gbar(unsigned* cnt, unsigned nb) {
    __syncthreads();
    if (threadIdx.x == 0) {
        aadd(cnt);
        while (aldu(cnt) < nb) __builtin_amdgcn_s_sleep(1);
    }
    __syncthreads();
}

// ---------------------------------------------------------------------------
// two-level device barrier (R16): 16-way group arrivals in parallel + 16-way
// root promoted by group leaders. All blocks release on root==16.
// ---------------------------------------------------------------------------
__device__ __forceinline__ void gbar2(unsigned* gslot, unsigned* root,
                                      int leader) {
    __syncthreads();
    if (threadIdx.x == 0) {
        aadd(gslot);
        if (leader) {
            while (aldu(gslot) < 16u) __builtin_amdgcn_s_sleep(1);
            aadd(root);
        }
        while (aldu(root) < 16u) __builtin_amdgcn_s_sleep(1);
    }
    __syncthreads();
}

// ---------------------------------------------------------------------------
// per-block: bitonic-sort deaths into LDS, emit sorted tolerance windows.
// 512 threads (1 elem/thread fill, 256 comparators/round).
// ---------------------------------------------------------------------------
__device__ void sort_windows(const float* __restrict__ deaths,
                             double* sd, double* slo, double* shi, int t) {
    if (t < NSORT) sd[t] = (t < NDEATH) ? (double)deaths[t] : 1e300;
    __syncthreads();
    for (int k = 2; k <= NSORT; k <<= 1) {
        for (int j = k >> 1; j > 0; j >>= 1) {
            if (t < 256) {
                int l = ((t & ~(j - 1)) << 1) | (t & (j - 1));   // pair (l, l+j)
                int p = l + j;
                bool up = ((l & k) == 0);
                double a = sd[l], b = sd[p];
                if ((a > b) == up) { sd[l] = b; sd[p] = a; }
            }
            __syncthreads();
        }
    }
    if (t < NSORT) {
        double d = sd[t];
        double w = ATOL_ + RTOL_ * fabs(d);
        slo[t] = d - w;
        shi[t] = d + w;
    }
    __syncthreads();
}

// ---------------------------------------------------------------------------
// f64 MFMA GEMM phase, R20: R16/R19 structure with K,N TEMPLATED and the
// kt-loop FULLY UNROLLED so the depth-3 prefetch ring indices (rs=kt%3,
// cur=kt&1) are compile-time constants -> ar[]/br[] SROA-promote to REGISTERS
// instead of scratch (rule #20: runtime-indexed arrays alloca to scratch; a
// scratch-resident br[] fed every MFMA B-operand through a ~600cy scratch
// load, the suspected ~2000cy/iter stall). Split-K x2 across wavegroups; A
// staged via LDS; B direct global->reg; two accumulators; one lgkm-only
// barrier per K-tile; s_setprio(1) around the MFMA cluster. Summation order
// identical to R16/R19 -> bit-identical numerics.
// ---------------------------------------------------------------------------
template <typename TIN, bool RELU, int N, int K>
__device__ void gemm_dev(const TIN* __restrict__ A, const float* __restrict__ W,
                         const float* __restrict__ bias, double* __restrict__ C,
                         int tile, int t,
                         double (&As)[2][2][KT][33]) {
    const int lane  = t & 63;
    const int wave4 = (t >> 6) & 3;     // quarter selector (same for both wg)
    const int w2    = t >> 8;           // wavegroup = K-half
    const int tg    = t & 255;          // 256-thread-local id for staging map
    const int wm    = wave4 & 1, wn = wave4 >> 1;
    constexpr int nbx = N >> 5;
    const int row0  = (tile / nbx) << 5;
    const int col0  = (tile % nbx) << 5;

    const int akk   = tg & 31;          // k within A tile
    const int amm   = tg >> 5;          // base row (rows amm+8p, p=0..3)
    const int kbase = w2 * (K >> 1);
    constexpr int nkt = K >> 6;         // K-tiles per wavegroup

    const int mrow  = wm * 16 + (lane & 15);
    const int ncol  = wn * 16 + (lane & 15);
    const int kq    = lane >> 4;

    TIN   ar[3][4];
    float br[3][8];

    auto load_a = [&](int rs, int kt) {
        const int k0 = kbase + (kt << 5);
        #pragma unroll
        for (int p = 0; p < 4; ++p)
            ar[rs][p] = A[(size_t)(row0 + amm + 8 * p) * K + k0 + akk];
    };
    auto load_b = [&](int rs, int kt) {
        const int k0 = kbase + (kt << 5);
        const float* wp = W + (size_t)(k0 + kq) * N + col0 + ncol;
        #pragma unroll
        for (int ks = 0; ks < 8; ++ks)
            br[rs][ks] = wp[(size_t)(4 * ks) * N];
    };
    auto stage_a = [&](int rs, int buf) {
        #pragma unroll
        for (int p = 0; p < 4; ++p)
            As[w2][buf][akk][amm + 8 * p] = (double)ar[rs][p];
    };

    load_a(0, 0); load_b(0, 0);
    if (nkt > 1) { load_a(1, 1); load_b(1, 1); }
    if (nkt > 2) { load_a(2, 2); load_b(2, 2); }
    stage_a(0, 0);
    lbar();

    d4_t c4a = {0.0, 0.0, 0.0, 0.0};
    d4_t c4b = {0.0, 0.0, 0.0, 0.0};

    #pragma unroll
    for (int kt = 0; kt < nkt; ++kt) {
        const int cur = kt & 1;      // compile-time under full unroll
        const int rs  = kt % 3;      // compile-time under full unroll
        __builtin_amdgcn_s_setprio(1);
        #pragma unroll
        for (int ks = 0; ks < 4; ++ks) {
            double av = As[w2][cur][ks * 4 + kq][mrow];
            c4a = __builtin_amdgcn_mfma_f64_16x16x4f64(av, (double)br[rs][ks],
                                                       c4a, 0, 0, 0);
        }
        #pragma unroll
        for (int ks = 4; ks < 8; ++ks) {
            double av = As[w2][cur][ks * 4 + kq][mrow];
            c4b = __builtin_amdgcn_mfma_f64_16x16x4f64(av, (double)br[rs][ks],
                                                       c4b, 0, 0, 0);
        }
        __builtin_amdgcn_s_setprio(0);
        // slot rs fully consumed -> refill for kt+3
        if (kt + 3 < nkt) { load_a(rs, kt + 3); load_b(rs, kt + 3); }
        if (kt + 1 < nkt) stage_a((kt + 1) % 3, cur ^ 1); // disjoint buffer
        lbar();                                           // lgkm-only
    }

    d4_t c4 = c4a + c4b;

    // combine K-half partials: kw1 publishes, kw0 adds + epilogue.
    // cEx aliases As (all K-loop reads fenced by the final loop barrier).
    double (*cEx)[16][17] = (double (*)[16][17])(&As[0][0][0][0]);
    const int r4 = (lane >> 4) * 4;
    if (w2 == 1) {
        #pragma unroll
        for (int r = 0; r < 4; ++r)
            cEx[wave4][r4 + r][lane & 15] = c4[r];
    }
    lbar();
    if (w2 == 0) {
        #pragma unroll
        for (int r = 0; r < 4; ++r) {
            int row = row0 + wm * 16 + r4 + r;
            int col = col0 + wn * 16 + (lane & 15);
            double v = c4[r] + cEx[wave4][r4 + r][lane & 15] + (double)bias[col];
            if (RELU) v = v > 0.0 ? v : 0.0;
            ast(&C[(size_t)row * N + col], v);
        }
    }
}

// ---------------------------------------------------------------------------
// column c: mean + target-MSE partial + compactness partial -> global slots
// 512 threads, one row per thread.
// ---------------------------------------------------------------------------
__device__ void mc_dev(const float* __restrict__ target,
                       const double* __restrict__ y,
                       double* __restrict__ t_part, double* __restrict__ c_part,
                       int c, int t) {
    const int wave = t >> 6, lane = t & 63;
    double v = y[(size_t)t * OUT_ + c];
    double s = v;
    for (int off = 32; off; off >>= 1) s += __shfl_down(s, off);
    __shared__ double swm[8];
    __shared__ double smean;
    if (lane == 0) swm[wave] = s;
    __syncthreads();
    if (t == 0) {
        double m = 0.0;
        #pragma unroll
        for (int w = 0; w < 8; ++w) m += swm[w];
        smean = m / (double)B_;
    }
    __syncthreads();
    double m = smean;
    double d = (double)target[(size_t)t * OUT_ + c] - v;
    double t_s = d * d;
    double c_s = fabs(v - m);
    for (int off = 32; off; off >>= 1) {
        t_s += __shfl_down(t_s, off);
        c_s += __shfl_down(c_s, off);
    }
    __shared__ double st[8], sc[8];
    if (lane == 0) { st[wave] = t_s; sc[wave] = c_s; }
    __syncthreads();
    if (t == 0) {
        double ts = 0.0, cs = 0.0;
        #pragma unroll
        for (int w = 0; w < 8; ++w) { ts += st[w]; cs += sc[w]; }
        ast(&t_part[c], ts);
        ast(&c_part[c], cs);
    }
}

// ---------------------------------------------------------------------------
// pdist + sorted-window match. Block b: rows b and 510-b (512 pairs, balanced).
// ---------------------------------------------------------------------------
__device__ __forceinline__ double pair_val(const double* __restrict__ yrow_s,
                                           const double* __restrict__ yj,
                                           const double* __restrict__ slo,
                                           const double* __restrict__ shi) {
    double s = 0.0;
    #pragma unroll
    for (int d = 0; d < OUT_; d += 2) {
        double2 v = *(const double2*)(yj + d);
        double d0 = yrow_s[d]     - v.x;
        double d1 = yrow_s[d + 1] - v.y;
        s = fma(d0, d0, s);
        s = fma(d1, d1, s);
    }
    double pd = sqrt(s);
    int pos = 0;
    #pragma unroll
    for (int step = NSORT / 2; step; step >>= 1) {
        if (slo[pos + step - 1] <= pd) pos += step;
    }
    bool m = (pos > 0) && (shi[pos - 1] >= pd);
    return m ? pd : 0.0;
}

__device__ void pdist_dev(const double* __restrict__ y,
                          double* __restrict__ hom_part, int bid, int t,
                          double* yA, double* yB,
                          const double* slo, const double* shi) {
    const int iA = bid;
    const int iB = 510 - bid;     // == iA when bid == 255
    if (t < OUT_)            yA[t]        = y[(size_t)iA * OUT_ + t];
    else if (t < 2 * OUT_)   yB[t - OUT_] = y[(size_t)iB * OUT_ + (t - OUT_)];
    __syncthreads();

    double local = 0.0;
    for (int j = iA + 1 + t; j < B_; j += NTHR)
        local += pair_val(yA, y + (size_t)j * OUT_, slo, shi);
    if (iB != iA)
        for (int j = iB + 1 + t; j < B_; j += NTHR)
            local += pair_val(yB, y + (size_t)j * OUT_, slo, shi);

    for (int off = 32; off; off >>= 1) local += __shfl_down(local, off);
    __shared__ double sw[8];
    int wave = t >> 6, lane = t & 63;
    if (lane == 0) sw[wave] = local;
    __syncthreads();
    if (t == 0) {
        double s = 0.0;
        #pragma unroll
        for (int w = 0; w < 8; ++w) s += sw[w];
        ast(&hom_part[bid], s);
    }
}

// ---------------------------------------------------------------------------
// single fused persistent kernel, R20: 256 blocks x 512 threads.
// XCD-LOCAL groups (R19): bid -> g=(bid&7)|((bid>>7)<<3), c=(bid>>3)&15
// (bijective); all 16 blocks of group g share bid%8 -> one XCD. Group g owns
// 32-row strip g; P0..P2 group-local 16-arrival barriers; two-level device
// barrier before pdist; two-level finalize with block 0 as fixed finalizer.
// Counters (uints): grp g slot p -> cnt[g*32+p] (p=0..4); pdist root cnt[512];
// finalize root cnt[513]. Window broadcast: wbc[0..511]=lo, wbc[512..1023]=hi.
// ---------------------------------------------------------------------------
__global__ __launch_bounds__(NTHR) void fused_k(
    const float* __restrict__ batch, const float* __restrict__ target,
    const float* __restrict__ W1, const float* __restrict__ b1,
    const float* __restrict__ W2, const float* __restrict__ b2,
    const float* __restrict__ W3, const float* __restrict__ b3,
    const float* __restrict__ Wout, const float* __restrict__ bout,
    const float* __restrict__ deaths, float* __restrict__ out,
    double* __restrict__ hA, double* __restrict__ hB,
    double* __restrict__ hC, double* __restrict__ yv,
    double* __restrict__ hom_part, double* __restrict__ t_part,
    double* __restrict__ c_part, unsigned* __restrict__ cnt,
    double* __restrict__ wbc) {
    const int bid = blockIdx.x;
    const int t   = threadIdx.x;
    const int g   = (bid & 7) | ((bid >> 7) << 3);  // XCD-local group
    const int c   = (bid >> 3) & 15;                // col-tile within group
    const int tile = g * 16 + c;                    // row0=32g, col0=32c
    unsigned* gc  = cnt + g * 32;                   // group counter line

    __shared__ double As[2][2][KT][33];
    __shared__ double slo[NSORT], shi[NSORT];
    __shared__ double yA[OUT_], yB[OUT_];
    double* sd = &As[0][0][0][0];             // sort scratch alias (512 dbl)

    // P0..P2: three GEMMs; tile (row0=32g, col0=32c).
    gemm_dev<float,  true, H_, IN_>(batch, W1, b1, hA, tile, t, As);
    gbar(&gc[0], 16);
    gemm_dev<double, true, H_, H_>(hA, W2, b2, hB, tile, t, As);
    gbar(&gc[1], 16);
    gemm_dev<double, true, H_, H_>(hB, W3, b3, hC, tile, t, As);
    gbar(&gc[2], 16);

    // P3: Wout tile g*2+c on c<2 (32-row strip g -> group-local dep, same
    // XCD); c>=2 sort. Block (g0,c2) publishes windows for the c<2 blocks.
    if (c < 2) {
        gemm_dev<double, false, OUT_, H_>(hC, Wout, bout, yv, g * 2 + c, t, As);
    } else {
        sort_windows(deaths, sd, slo, shi, t);
        if (g == 0 && c == 2 && t < NSORT) {
            ast(&wbc[t],         slo[t]);
            ast(&wbc[NSORT + t], shi[t]);
        }
    }

    // two-level device barrier: pdist needs all of yv + window broadcast
    gbar2(&gc[3], &cnt[512], c == 0);
    if (c < 2) {
        if (t < NSORT) {
            slo[t] = ald(&wbc[t]);
            shi[t] = ald(&wbc[NSORT + t]);
        }
        __syncthreads();
    }

    // P4: pdist on all 256 blocks; mean/MSE/compactness on blocks 0..63
    pdist_dev(yv, hom_part, bid, t, yA, yB, slo, shi);
    if (bid < OUT_) mc_dev(target, yv, t_part, c_part, bid, t);

    // P5: two-level finalize arrivals; block 0 is the fixed finalizer.
    __syncthreads();   // vmcnt(0) drain: part stores visible before arrival
    if (t == 0) {
        aadd(&gc[4]);
        if (c == 0) {
            while (aldu(&gc[4]) < 16u) __builtin_amdgcn_s_sleep(1);
            aadd(&cnt[513]);
        }
    }
    if (bid != 0) return;
    if (t == 0)
        while (aldu(&cnt[513]) < 16u) __builtin_amdgcn_s_sleep(1);
    __syncthreads();

    {
        double h = 0.0, tp = 0.0, cp = 0.0;
        if (t < NBLK) h = ald(&hom_part[t]);
        if (t < OUT_) { tp = ald(&t_part[t]); cp = ald(&c_part[t]); }
        for (int off = 32; off; off >>= 1) {
            h  += __shfl_down(h,  off);
            tp += __shfl_down(tp, off);
            cp += __shfl_down(cp, off);
        }
        __shared__ double sh[8], stp[8], scp[8];
        int wave = t >> 6, lane = t & 63;
        if (lane == 0) { sh[wave] = h; stp[wave] = tp; scp[wave] = cp; }
        __syncthreads();
        if (t == 0) {
            double hs = 0.0, ts = 0.0, cs = 0.0;
            #pragma unroll
            for (int w = 0; w < 8; ++w) {
                hs += sh[w]; ts += stp[w]; cs += scp[w];
            }
            out[0] = (float)(ts / (double)(B_ * OUT_) + hs + 0.01 * cs);
        }
    }
}

extern "C" void kernel_launch(void* const* d_in, const int* in_sizes, int n_in,
                              void* d_out, int out_size, void* d_ws, size_t ws_size,
                              hipStream_t stream) {
    const float* batch  = (const float*)d_in[0];
    const float* target = (const float*)d_in[1];
    const float* W1     = (const float*)d_in[2];
    const float* b1     = (const float*)d_in[3];
    const float* W2     = (const float*)d_in[4];
    const float* b2     = (const float*)d_in[5];
    const float* W3     = (const float*)d_in[6];
    const float* b3     = (const float*)d_in[7];
    const float* Wout   = (const float*)d_in[8];
    const float* bout   = (const float*)d_in[9];
    const float* deaths = (const float*)d_in[10];
    float* out = (float*)d_out;

    double* hA       = (double*)d_ws;              // 512*512
    double* hB       = hA + (size_t)B_ * H_;       // 512*512
    double* hC       = hB + (size_t)B_ * H_;       // 512*512
    double* yv       = hC + (size_t)B_ * H_;       // 512*64
    double* hom_part = yv + (size_t)B_ * OUT_;     // 256
    double* t_part   = hom_part + NBLK;            // 64
    double* c_part   = t_part + OUT_;              // 64
    unsigned* cnt    = (unsigned*)(c_part + OUT_); // 576 uints
    double* wbc      = (double*)(cnt + 576);       // 1024 doubles (lo|hi)

    hipMemsetAsync(cnt, 0, 576 * sizeof(unsigned), stream);

    fused_k<<<dim3(NBLK), dim3(NTHR), 0, stream>>>(
        batch, target, W1, b1, W2, b2, W3, b3, Wout, bout, deaths, out,
        hA, hB, hC, yv, hom_part, t_part, c_part, cnt, wbc);
}